// Round 15
// baseline (107.574 us; speedup 1.0000x reference)
//
#include <hip/hip_runtime.h>
#include <hip/hip_fp16.h>

// Deformable Conv2d — MI355X, round 15
// vs R14: double-buffered offset/mask burst. Each tile previously began with
// 30 just-in-time global loads -> ~600-900 cy exposed latency per tile with
// only ~2.3 waves/SIMD to hide it (the "nothing busy, nothing helps" stall).
// Now tile s+1's 30 loads are issued BEFORE tile s's compute and stay in
// flight through it (T14 issue-early/consume-late); sigmoid moved to consume
// time; tile loop fully unrolled so buffer roll is an SSA rename.

#define KSZ 3
#define PAD 1

static constexpr int B   = 4;
static constexpr int Cin = 64;
static constexpr int H   = 256;
static constexpr int W   = 256;
static constexpr int G   = 8;
static constexpr int OC  = 64;
static constexpr int KK  = KSZ * KSZ;  // 9
static constexpr int Cpg = Cin / G;    // 8
static constexpr int OPG = OC / G;     // 8
static constexpr int HW  = H * W;
static constexpr int NXCD = 8;

static constexpr int BR    = 4;        // output rows per tile
static constexpr int TPB   = 4;        // tiles per block (16 rows)
static constexpr int BC    = 64;       // output cols per tile
static constexpr int WRING = 16;       // ring rows (y & 15)
static constexpr int WCOLS = 75;       // 16B slots per ring row

typedef _Float16 f16x8  __attribute__((ext_vector_type(8)));
typedef float    f32x16 __attribute__((ext_vector_type(16)));

union U4H {
    uint4 u;
    __half2 h2[4];
    _Float16 h[8];
    f16x8 v;
};

// ---- transpose: x [B,Cin,H,W] f32 -> xt [B,G,H,W,Cpg] fp16 (16B/pixel) ----
__global__ __launch_bounds__(256) void transpose_kernel(
    const float* __restrict__ x, uint4* __restrict__ xt)
{
    const int h = blockIdx.x, g = blockIdx.y, b = blockIdx.z;
    const int w = threadIdx.x;
    const int pix = h * W + w;
    const float* src = x + (size_t)(b * Cin + g * Cpg) * HW + pix;
    U4H v;
#pragma unroll
    for (int c = 0; c < 8; ++c) v.h[c] = (_Float16)src[(size_t)c * HW];
    xt[(size_t)(b * G + g) * HW + pix] = v.u;
}

// ---- prep: per-lane MFMA A-fragments, layout [g][m][lane] (40 KB) ----
__global__ __launch_bounds__(320) void prep_weights(
    const float* __restrict__ weight, uint4* __restrict__ wfrag)
{
    const int g    = blockIdx.x;
    const int tid  = threadIdx.x;     // 0..319
    const int m    = tid >> 6;        // 0..4
    const int lane = tid & 63;
    const int hi   = lane >> 5;
    const int lp   = lane & 31;
    const int t    = 2 * m + hi;
    U4H a;
#pragma unroll
    for (int c = 0; c < 8; ++c) {
        float v = 0.0f;
        if (lp < OPG && t < KK)
            v = weight[((size_t)(g * OPG + lp) * Cpg + c) * KK + t];
        a.h[c] = (_Float16)v;
    }
    wfrag[((size_t)g * 5 + m) * 64 + lane] = a.u;
}

// ---- main kernel: 256 threads, 4 tiles of 4 rows x 64 cols per block ----
__global__ __launch_bounds__(256) void dcn_kernel(
    const uint4* __restrict__ xt,
    const uint4* __restrict__ wfrag,
    const float* __restrict__ offset,
    const float* __restrict__ mask,
    const float* __restrict__ bias,
    float* __restrict__ out)
{
    __shared__ uint4 win[WRING * WCOLS];   // 19,200 B

    // XCD-chunked bijective swizzle (2048 blocks % 8 == 0)
    const unsigned id = blockIdx.x;
    const unsigned wl = (id & (NXCD - 1)) * (gridDim.x / NXCD) + (id >> 3);
    const int q      = wl & 15;               // row-quad (16 rows)
    const int colblk = (wl >> 4) & 3;
    const int g      = (wl >> 6) & (G - 1);
    const int b      = wl >> 9;

    const int h_start = q * (BR * TPB);
    const int xbase   = colblk * BC;
    const int x0base  = xbase - 5;

    const int tid  = threadIdx.x;
    const int lane = tid & 63;
    const int wave = tid >> 6;                // 0..3 -> row within tile
    const int hi   = lane >> 5;               // tap parity in MFMA k dim
    const int lp   = lane & 31;               // A-row (out ch) / B-col (pixel)

    const uint4* xb = xt + (size_t)(b * G + g) * HW;

    // ---- initial stage: ring rows h_start-5 .. h_start+10 (zero-staged) ----
#pragma unroll
    for (int it = 0; it < 5; ++it) {
        const int k = it * 256 + tid;
        if (k < WRING * WCOLS) {
            const int i = k / WCOLS;
            const int j = k - i * WCOLS;
            const int y  = h_start - 5 + i;
            const int gc = x0base + j;
            const bool vld = ((unsigned)y < (unsigned)H) & ((unsigned)gc < (unsigned)W);
            const int yc = min(max(y, 0), H - 1);
            const int gcc = min(max(gc, 0), W - 1);
            uint4 val = xb[yc * W + gcc];
            if (!vld) val = make_uint4(0, 0, 0, 0);
            win[(y & 15) * WCOLS + j] = val;
        }
    }

    // A-fragments: 5 coalesced dwordx4 loads (precomputed by prep_weights)
    f16x8 afrag[5];
    {
        const uint4* wf = wfrag + (size_t)g * 5 * 64 + lane;
#pragma unroll
        for (int m = 0; m < 5; ++m) {
            U4H tmp; tmp.u = wf[m * 64];
            afrag[m] = tmp.v;
        }
    }

    const float* offy = offset + (size_t)(b * 2 + 0) * (G * KK) * HW;
    const float* offx = offset + (size_t)(b * 2 + 1) * (G * KK) * HW;
    const float* mk   = mask + (size_t)b * (G * KK) * HW;

    // per-m plane offsets (lane-dependent via hi only)
    int oIdx[5], mIdx[5];
#pragma unroll
    for (int m = 0; m < 5; ++m) {
        const int t  = 2 * m + hi;
        const int tt = (t > 8) ? 8 : t;
        oIdx[m] = (G * KK - 1 - (g * KK + tt)) * HW;   // flipped tap axis
        mIdx[m] = (g * KK + tt) * HW;
    }

    // one tap: bilinear blend of 4 corners from the ring window
    auto sample = [&](int hb5, float py, float px, float ms) -> f16x8 {
        const float y0f = floorf(py), x0f = floorf(px);
        const float wy = py - y0f, wx = px - x0f;
        const int y0  = (int)y0f, x0 = (int)x0f;
        const int ix0 = x0 - x0base;
        const bool ok = ((unsigned)(y0 - hb5) <= 14u) & ((unsigned)ix0 <= 72u);
        int a0 = (y0 & 15) * WCOLS + ix0;
        int a1 = ((y0 + 1) & 15) * WCOLS + ix0;
        a0 = ok ? a0 : 0;
        a1 = ok ? a1 : 0;
        uint4 c00 = win[a0], c01 = win[a0 + 1];
        uint4 c10 = win[a1], c11 = win[a1 + 1];

        const float u  = (1.f - wy) * ms;
        const float vv = wy * ms;
        float w00 = u * (1.f - wx), w01 = u * wx;
        float w10 = vv * (1.f - wx), w11 = vv * wx;

        if (__builtin_expect(!__all((int)ok), 0)) {    // |offset| > ~4
            if (!ok) {
                const bool vy0 = (unsigned)y0 < (unsigned)H;
                const bool vy1 = (unsigned)(y0 + 1) < (unsigned)H;
                const bool vx0 = (unsigned)x0 < (unsigned)W;
                const bool vx1 = (unsigned)(x0 + 1) < (unsigned)W;
                const float uu = vy0 ? u : 0.f,  vz = vy1 ? vv : 0.f;
                const float ca = vx0 ? (1.f - wx) : 0.f;
                const float cb = vx1 ? wx : 0.f;
                w00 = uu * ca; w01 = uu * cb; w10 = vz * ca; w11 = vz * cb;
                const int yc0 = min(max(y0, 0), H - 1), yc1 = min(max(y0 + 1, 0), H - 1);
                const int xc0 = min(max(x0, 0), W - 1), xc1 = min(max(x0 + 1, 0), W - 1);
                c00 = xb[yc0 * W + xc0]; c01 = xb[yc0 * W + xc1];
                c10 = xb[yc1 * W + xc0]; c11 = xb[yc1 * W + xc1];
            }
        }

        U4H a, bq, c, d; a.u = c00; bq.u = c01; c.u = c10; d.u = c11;
        const __half2 h00 = __float2half2_rn(w00);
        const __half2 h01 = __float2half2_rn(w01);
        const __half2 h10 = __float2half2_rn(w10);
        const __half2 h11 = __float2half2_rn(w11);
        U4H s;
#pragma unroll
        for (int i = 0; i < 4; ++i)
            s.h2[i] = __hfma2(h00, a.h2[i],
                      __hfma2(h01, bq.h2[i],
                      __hfma2(h10, c.h2[i],
                      __hmul2(h11, d.h2[i]))));
        return s.v;
    };

    // ---- tile-0 offset/mask burst (raw mask; sigmoid at consume) ----
    float dyC[2][5], dxC[2][5], mvC[2][5];
    {
        const int h0r = h_start + wave;
#pragma unroll
        for (int tile = 0; tile < 2; ++tile) {
            const int pix = h0r * W + xbase + tile * 32 + lp;
#pragma unroll
            for (int m = 0; m < 5; ++m) {
                dyC[tile][m] = offy[oIdx[m] + pix];
                dxC[tile][m] = offx[oIdx[m] + pix];
                mvC[tile][m] = mk[mIdx[m] + pix];
            }
        }
    }

    __syncthreads();   // initial window ready

    // ring prefetch bookkeeping (slots tid and 256+tid of 300)
    const int pi0 = tid / WCOLS, pj0 = tid - pi0 * WCOLS;
    const int k1  = 256 + tid;
    const int pi1 = k1 / WCOLS, pj1 = k1 - pi1 * WCOLS;
    const bool has1 = (tid < 44);

#pragma unroll
    for (int s = 0; s < TPB; ++s) {
        const int h_base = h_start + BR * s;
        const int h   = h_base + wave;
        const int hb5 = h_base - 5;

        // (1) issue next-4-rows ring prefetch (oldest in vmcnt queue)
        uint4 pf0 = make_uint4(0, 0, 0, 0), pf1 = make_uint4(0, 0, 0, 0);
        int yA = 0, yB = 0;
        bool pv0 = false, pv1 = false;
        if (s < TPB - 1) {
            yA = h_base + 11 + pi0;
            const int gcA = x0base + pj0;
            pv0 = ((unsigned)yA < (unsigned)H) & ((unsigned)gcA < (unsigned)W);
            pf0 = xb[min(max(yA, 0), H - 1) * W + min(max(gcA, 0), W - 1)];
            if (has1) {
                yB = h_base + 11 + pi1;
                const int gcB = x0base + pj1;
                pv1 = ((unsigned)yB < (unsigned)H) & ((unsigned)gcB < (unsigned)W);
                pf1 = xb[min(max(yB, 0), H - 1) * W + min(max(gcB, 0), W - 1)];
            }
        }

        // (2) issue NEXT tile's offset/mask burst — in flight across compute
        float dyN[2][5], dxN[2][5], mvN[2][5];
#pragma unroll
        for (int tile = 0; tile < 2; ++tile) {
#pragma unroll
            for (int m = 0; m < 5; ++m) {
                dyN[tile][m] = 0.f; dxN[tile][m] = 0.f; mvN[tile][m] = 0.f;
            }
        }
        if (s < TPB - 1) {
            const int hn = h + BR;
#pragma unroll
            for (int tile = 0; tile < 2; ++tile) {
                const int pix = hn * W + xbase + tile * 32 + lp;
#pragma unroll
                for (int m = 0; m < 5; ++m) {
                    dyN[tile][m] = offy[oIdx[m] + pix];
                    dxN[tile][m] = offx[oIdx[m] + pix];
                    mvN[tile][m] = mk[mIdx[m] + pix];
                }
            }
        }

        // (3) sigmoid + pad fold for current tile
        float msv[2][5];
#pragma unroll
        for (int tile = 0; tile < 2; ++tile) {
#pragma unroll
            for (int m = 0; m < 5; ++m) {
                const int t = 2 * m + hi;
                const float sg = 1.0f / (1.0f + __expf(-mvC[tile][m]));
                msv[tile][m] = (t <= 8) ? sg : 0.0f;
            }
        }

        // (4) compute: 10 taps x 2 tiles, MFMA accumulate
        f32x16 acc0 = {};
        f32x16 acc1 = {};
#pragma unroll
        for (int m = 0; m < 5; ++m) {
            const int t  = 2 * m + hi;
            const int tt = (t > 8) ? 8 : t;
            const int ki = (tt >= 3) + (tt >= 6);
            const int kj = tt - 3 * ki;
            const float pyb = (float)(h - PAD + ki);
            const float pxb = (float)(xbase + lp - PAD + kj);
            acc0 = __builtin_amdgcn_mfma_f32_32x32x16_f16(
                afrag[m], sample(hb5, pyb + dyC[0][m], pxb + dxC[0][m], msv[0][m]), acc0, 0, 0, 0);
            acc1 = __builtin_amdgcn_mfma_f32_32x32x16_f16(
                afrag[m], sample(hb5, pyb + dyC[1][m], pxb + 32.0f + dxC[1][m], msv[1][m]), acc1, 0, 0, 0);
        }

        // (5) store: C col = lp, row = (reg&3)+8*(reg>>2)+4*hi -> d = reg+4*hi
#pragma unroll
        for (int tile = 0; tile < 2; ++tile) {
            const int wq = xbase + tile * 32 + lp;
#pragma unroll
            for (int r = 0; r < 4; ++r) {
                const int dd = r + 4 * hi;
                const float v = (tile == 0 ? acc0[r] : acc1[r]) + bias[g * OPG + dd];
                out[((size_t)b * OC + g * OPG + dd) * HW + h * W + wq] = v;
            }
        }

        __syncthreads();   // all reads of old ring rows done
        if (s < TPB - 1) {
            win[(yA & 15) * WCOLS + pj0] = pv0 ? pf0 : make_uint4(0, 0, 0, 0);
            if (has1)
                win[(yB & 15) * WCOLS + pj1] = pv1 ? pf1 : make_uint4(0, 0, 0, 0);
        }
        __syncthreads();   // new rows visible

        // (6) roll buffers (SSA rename — loop fully unrolled, static indices)
#pragma unroll
        for (int tile = 0; tile < 2; ++tile) {
#pragma unroll
            for (int m = 0; m < 5; ++m) {
                dyC[tile][m] = dyN[tile][m];
                dxC[tile][m] = dxN[tile][m];
                mvC[tile][m] = mvN[tile][m];
            }
        }
    }
}

extern "C" void kernel_launch(void* const* d_in, const int* in_sizes, int n_in,
                              void* d_out, int out_size, void* d_ws, size_t ws_size,
                              hipStream_t stream) {
    const float* x      = (const float*)d_in[0];
    const float* offset = (const float*)d_in[1];
    const float* mask   = (const float*)d_in[2];
    const float* weight = (const float*)d_in[3];
    const float* bias   = (const float*)d_in[4];
    float* out = (float*)d_out;

    uint4* xt    = (uint4*)d_ws;                                      // 32 MiB
    uint4* wfrag = (uint4*)((char*)d_ws + (size_t)B * G * HW * 16);   // 40 KiB

    dim3 tgrid(H, G, B);
    transpose_kernel<<<tgrid, dim3(256), 0, stream>>>(x, xt);
    prep_weights<<<dim3(G), dim3(320), 0, stream>>>(weight, wfrag);
    // B*G * (H/16 row-quads) * (W/64 col-blocks) = 2048 blocks
    dcn_kernel<<<dim3(B * G * (H / (BR * TPB)) * (W / BC)), dim3(256), 0, stream>>>(
        xt, wfrag, offset, mask, bias, out);
}

// Round 16
// 99.395 us; speedup vs baseline: 1.0823x; 1.0823x over previous
//
#include <hip/hip_runtime.h>
#include <hip/hip_fp16.h>

// Deformable Conv2d — MI355X, round 16
// vs R11: identical block/window structure (4 rows x 64 cols, 15x75 window,
// 18 KB, 8192 blocks), but the 5-step m-loop is ROLLED (#pragma unroll 1)
// with a depth-1 software pipeline (next iter's 6 offset/mask loads + 1
// wfrag load issued before current iter's compute) and the rare slow path
// factored into a __noinline__ cold function. Hot loop ~120 instrs vs the
// previous multi-KB 10x-unrolled body — tests the I$-pressure hypothesis
// (no pipe >45% yet structure-insensitive; only instruction-count cuts have
// ever helped).

#define KSZ 3
#define PAD 1

static constexpr int B   = 4;
static constexpr int Cin = 64;
static constexpr int H   = 256;
static constexpr int W   = 256;
static constexpr int G   = 8;
static constexpr int OC  = 64;
static constexpr int KK  = KSZ * KSZ;  // 9
static constexpr int Cpg = Cin / G;    // 8
static constexpr int OPG = OC / G;     // 8
static constexpr int HW  = H * W;
static constexpr int NXCD = 8;

static constexpr int BR    = 4;        // output rows per block
static constexpr int BC    = 64;       // output cols per block
static constexpr int MARG  = 5;
static constexpr int WROWS = BR + 2 * MARG + 1;  // 15
static constexpr int WCOLS = 75;                 // 16B slots/row
static constexpr int WUSED = BC + 2 * MARG;      // 74

typedef _Float16 f16x8  __attribute__((ext_vector_type(8)));
typedef float    f32x16 __attribute__((ext_vector_type(16)));

union U4H {
    uint4 u;
    __half2 h2[4];
    _Float16 h[8];
    f16x8 v;
};

// ---- transpose: x [B,Cin,H,W] f32 -> xt [B,G,H,W,Cpg] fp16 (16B/pixel) ----
__global__ __launch_bounds__(256) void transpose_kernel(
    const float* __restrict__ x, uint4* __restrict__ xt)
{
    const int h = blockIdx.x, g = blockIdx.y, b = blockIdx.z;
    const int w = threadIdx.x;
    const int pix = h * W + w;
    const float* src = x + (size_t)(b * Cin + g * Cpg) * HW + pix;
    U4H v;
#pragma unroll
    for (int c = 0; c < 8; ++c) v.h[c] = (_Float16)src[(size_t)c * HW];
    xt[(size_t)(b * G + g) * HW + pix] = v.u;
}

// ---- prep: per-lane MFMA A-fragments, layout [g][m][lane] (40 KB) ----
__global__ __launch_bounds__(320) void prep_weights(
    const float* __restrict__ weight, uint4* __restrict__ wfrag)
{
    const int g    = blockIdx.x;
    const int tid  = threadIdx.x;     // 0..319
    const int m    = tid >> 6;        // 0..4
    const int lane = tid & 63;
    const int hi   = lane >> 5;
    const int lp   = lane & 31;
    const int t    = 2 * m + hi;
    U4H a;
#pragma unroll
    for (int c = 0; c < 8; ++c) {
        float v = 0.0f;
        if (lp < OPG && t < KK)
            v = weight[((size_t)(g * OPG + lp) * Cpg + c) * KK + t];
        a.h[c] = (_Float16)v;
    }
    wfrag[((size_t)g * 5 + m) * 64 + lane] = a.u;
}

// ---- cold path: boundary weights + global gathers + blend (rare) ----
__device__ __attribute__((noinline)) f16x8 slow_sample(
    const uint4* __restrict__ xb, int y0, int x0, float wy, float wx, float ms)
{
    const bool vy0 = (unsigned)y0 < (unsigned)H;
    const bool vy1 = (unsigned)(y0 + 1) < (unsigned)H;
    const bool vx0 = (unsigned)x0 < (unsigned)W;
    const bool vx1 = (unsigned)(x0 + 1) < (unsigned)W;
    const float u  = vy0 ? (1.f - wy) * ms : 0.f;
    const float vv = vy1 ? wy * ms : 0.f;
    const float ca = vx0 ? (1.f - wx) : 0.f;
    const float cb = vx1 ? wx : 0.f;
    const float w00 = u * ca, w01 = u * cb, w10 = vv * ca, w11 = vv * cb;
    const int yc0 = min(max(y0, 0), H - 1), yc1 = min(max(y0 + 1, 0), H - 1);
    const int xc0 = min(max(x0, 0), W - 1), xc1 = min(max(x0 + 1, 0), W - 1);
    U4H a, bq, c, d;
    a.u  = xb[yc0 * W + xc0];
    bq.u = xb[yc0 * W + xc1];
    c.u  = xb[yc1 * W + xc0];
    d.u  = xb[yc1 * W + xc1];
    const __half2 h00 = __float2half2_rn(w00);
    const __half2 h01 = __float2half2_rn(w01);
    const __half2 h10 = __float2half2_rn(w10);
    const __half2 h11 = __float2half2_rn(w11);
    U4H s;
#pragma unroll
    for (int i = 0; i < 4; ++i)
        s.h2[i] = __hfma2(h00, a.h2[i],
                  __hfma2(h01, bq.h2[i],
                  __hfma2(h10, c.h2[i],
                  __hmul2(h11, d.h2[i]))));
    return s.v;
}

// ---- main kernel: 256 threads, 4 rows x 64 cols per block ----
__global__ __launch_bounds__(256) void dcn_kernel(
    const uint4* __restrict__ xt,
    const uint4* __restrict__ wfrag,
    const float* __restrict__ offset,
    const float* __restrict__ mask,
    const float* __restrict__ bias,
    float* __restrict__ out)
{
    __shared__ uint4 win[WROWS * WCOLS];   // 18,000 B

    // XCD-chunked bijective swizzle (8192 blocks % 8 == 0)
    const unsigned id = blockIdx.x;
    const unsigned wl = (id & (NXCD - 1)) * (gridDim.x / NXCD) + (id >> 3);
    const int colblk = wl & 3;
    const int rowblk = (wl >> 2) & 63;
    const int g      = (wl >> 8) & (G - 1);
    const int b      = wl >> 11;

    const int h_base = rowblk * BR;
    const int xbase  = colblk * BC;
    const int h0     = h_base - MARG;
    const int x0base = xbase - MARG;

    const int tid  = threadIdx.x;
    const int lane = tid & 63;
    const int wave = tid >> 6;                // 0..3 -> output row
    const int hi   = lane >> 5;               // tap parity in MFMA k dim
    const int lp   = lane & 31;               // A-row (out ch) / B-col (pixel)

    const int h = h_base + wave;

    const uint4* xb = xt + (size_t)(b * G + g) * HW;

    // ---- stage the 15x74 window; out-of-image slots get ZERO ----
#pragma unroll
    for (int it = 0; it < 5; ++it) {
        const int k = it * 256 + tid;
        if (k < WROWS * WCOLS) {
            const int i = k / WCOLS;
            const int j = k - i * WCOLS;
            const int gr = h0 + i;
            const int gc = x0base + j;
            const bool vld = ((unsigned)gr < (unsigned)H) & ((unsigned)gc < (unsigned)W);
            const int grc = min(max(gr, 0), H - 1);
            const int gcc = min(max(gc, 0), W - 1);
            uint4 val = xb[grc * W + gcc];
            if (!vld) val = make_uint4(0, 0, 0, 0);
            win[k] = val;
        }
    }

    const float* offy = offset + (size_t)(b * 2 + 0) * (G * KK) * HW;
    const float* offx = offset + (size_t)(b * 2 + 1) * (G * KK) * HW;
    const float* mk   = mask + (size_t)b * (G * KK) * HW;
    const uint4* wfb  = wfrag + (size_t)g * 5 * 64 + lane;

    const int pix0 = h * W + xbase + lp;
    const int pix1 = pix0 + 32;

    // ---- prologue: m=0 loads ----
    float dy0c, dx0c, mv0c, dy1c, dx1c, mv1c;
    U4H afc;
    {
        const int t0  = hi;                    // 2*0 + hi
        const int oI = (G * KK - 1 - (g * KK + t0)) * HW;
        const int mI = (g * KK + t0) * HW;
        dy0c = offy[oI + pix0];  dx0c = offx[oI + pix0];  mv0c = mk[mI + pix0];
        dy1c = offy[oI + pix1];  dx1c = offx[oI + pix1];  mv1c = mk[mI + pix1];
        afc.u = wfb[0];
    }

    __syncthreads();   // window ready

    // hot sample: 2-compare predicate, 4 window reads, packed blend
    auto sample = [&](float py, float px, float ms) -> f16x8 {
        const float y0f = floorf(py), x0f = floorf(px);
        const float wy = py - y0f, wx = px - x0f;
        const int y0 = (int)y0f, x0 = (int)x0f;
        const int iy0 = y0 - h0;
        const int ix0 = x0 - x0base;
        const bool ok = ((unsigned)iy0 <= (unsigned)(WROWS - 2)) &
                        ((unsigned)ix0 <= (unsigned)(WUSED - 2));
        int a0 = iy0 * WCOLS + ix0;
        a0 = ok ? a0 : 0;
        U4H a, bq, c, d;
        a.u  = win[a0];          bq.u = win[a0 + 1];
        c.u  = win[a0 + WCOLS];  d.u  = win[a0 + WCOLS + 1];
        const float u  = (1.f - wy) * ms;
        const float vv = wy * ms;
        const float w00 = u * (1.f - wx), w01 = u * wx;
        const float w10 = vv * (1.f - wx), w11 = vv * wx;
        const __half2 h00 = __float2half2_rn(w00);
        const __half2 h01 = __float2half2_rn(w01);
        const __half2 h10 = __float2half2_rn(w10);
        const __half2 h11 = __float2half2_rn(w11);
        U4H s;
#pragma unroll
        for (int i = 0; i < 4; ++i)
            s.h2[i] = __hfma2(h00, a.h2[i],
                      __hfma2(h01, bq.h2[i],
                      __hfma2(h10, c.h2[i],
                      __hmul2(h11, d.h2[i]))));
        f16x8 res = s.v;
        if (__builtin_expect(!__all((int)ok), 0)) {     // |offset| > ~4.5
            if (!ok) res = slow_sample(xb, y0, x0, wy, wx, ms);
        }
        return res;
    };

    f32x16 acc0 = {};
    f32x16 acc1 = {};

#pragma unroll 1
    for (int m = 0; m < 5; ++m) {
        // ---- issue next-iter loads (redundant re-load of m=4 on last) ----
        const int mn  = (m < 4) ? m + 1 : 4;
        const int tn  = 2 * mn + hi;
        const int ttn = (tn > 8) ? 8 : tn;
        const int oIn = (G * KK - 1 - (g * KK + ttn)) * HW;
        const int mIn = (g * KK + ttn) * HW;
        const float dy0n = offy[oIn + pix0];
        const float dx0n = offx[oIn + pix0];
        const float mv0n = mk[mIn + pix0];
        const float dy1n = offy[oIn + pix1];
        const float dx1n = offx[oIn + pix1];
        const float mv1n = mk[mIn + pix1];
        U4H afn; afn.u = wfb[mn * 64];

        // ---- compute current ----
        const int t  = 2 * m + hi;
        const int tt = (t > 8) ? 8 : t;
        const int ki = (tt >= 3) + (tt >= 6);
        const int kj = tt - 3 * ki;
        const float pyb = (float)(h - PAD + ki);
        const float pxb = (float)(xbase + lp - PAD + kj);

        float sg0 = 1.0f / (1.0f + __expf(-mv0c));
        float sg1 = 1.0f / (1.0f + __expf(-mv1c));
        sg0 = (t <= 8) ? sg0 : 0.0f;
        sg1 = (t <= 8) ? sg1 : 0.0f;

        acc0 = __builtin_amdgcn_mfma_f32_32x32x16_f16(
            afc.v, sample(pyb + dy0c, pxb + dx0c, sg0), acc0, 0, 0, 0);
        acc1 = __builtin_amdgcn_mfma_f32_32x32x16_f16(
            afc.v, sample(pyb + dy1c, pxb + 32.0f + dx1c, sg1), acc1, 0, 0, 0);

        // ---- roll ----
        dy0c = dy0n; dx0c = dx0n; mv0c = mv0n;
        dy1c = dy1n; dx1c = dx1n; mv1c = mv1n;
        afc = afn;
    }

    // C layout: col = lp (pixel), row = (reg&3) + 8*(reg>>2) + 4*hi.
    // Useful rows 0..7 -> out channel d = reg + 4*hi (regs 0..3).
#pragma unroll
    for (int tile = 0; tile < 2; ++tile) {
        const int wq = xbase + tile * 32 + lp;
#pragma unroll
        for (int r = 0; r < 4; ++r) {
            const int dd = r + 4 * hi;
            const float v = (tile == 0 ? acc0[r] : acc1[r]) + bias[g * OPG + dd];
            out[((size_t)b * OC + g * OPG + dd) * HW + h * W + wq] = v;
        }
    }
}

extern "C" void kernel_launch(void* const* d_in, const int* in_sizes, int n_in,
                              void* d_out, int out_size, void* d_ws, size_t ws_size,
                              hipStream_t stream) {
    const float* x      = (const float*)d_in[0];
    const float* offset = (const float*)d_in[1];
    const float* mask   = (const float*)d_in[2];
    const float* weight = (const float*)d_in[3];
    const float* bias   = (const float*)d_in[4];
    float* out = (float*)d_out;

    uint4* xt    = (uint4*)d_ws;                                      // 32 MiB
    uint4* wfrag = (uint4*)((char*)d_ws + (size_t)B * G * HW * 16);   // 40 KiB

    dim3 tgrid(H, G, B);
    transpose_kernel<<<tgrid, dim3(256), 0, stream>>>(x, xt);
    prep_weights<<<dim3(G), dim3(320), 0, stream>>>(weight, wfrag);
    dcn_kernel<<<dim3(B * G * (H / BR) * (W / BC)), dim3(256), 0, stream>>>(
        xt, wfrag, offset, mask, bias, out);
}

// Round 17
// 96.657 us; speedup vs baseline: 1.1129x; 1.0283x over previous
//
#include <hip/hip_runtime.h>
#include <hip/hip_fp16.h>

// Deformable Conv2d — MI355X, round 17
// vs R16: 4 MFMA tiles per wave (one row x 128 cols) instead of 2. The
// 16-round record shows resident waves pin at ~15/CU regardless of
// structure, and time scales with work-per-wave (R9: half work -> 1.7x
// slower). So: double work per wave at constant residency. Window 15x139
// (33.4 KB, 4 blocks/CU), grid 4096, rolled m-loop with depth-1 prefetch
// (R16's proven hot path), 4 samples + 4 MFMAs per iteration.

#define KSZ 3
#define PAD 1

static constexpr int B   = 4;
static constexpr int Cin = 64;
static constexpr int H   = 256;
static constexpr int W   = 256;
static constexpr int G   = 8;
static constexpr int OC  = 64;
static constexpr int KK  = KSZ * KSZ;  // 9
static constexpr int Cpg = Cin / G;    // 8
static constexpr int OPG = OC / G;     // 8
static constexpr int HW  = H * W;
static constexpr int NXCD = 8;

static constexpr int BR    = 4;        // output rows per block (1 per wave)
static constexpr int BC    = 128;      // output cols per block (4 tiles)
static constexpr int MARG  = 5;
static constexpr int WROWS = BR + 2 * MARG + 1;  // 15
static constexpr int WCOLS = 139;                // 138 used + 1 spare
static constexpr int WUSED = BC + 2 * MARG;      // 138
static constexpr int WSLOTS = WROWS * WCOLS;     // 2085

typedef _Float16 f16x8  __attribute__((ext_vector_type(8)));
typedef float    f32x16 __attribute__((ext_vector_type(16)));

union U4H {
    uint4 u;
    __half2 h2[4];
    _Float16 h[8];
    f16x8 v;
};

// ---- transpose: x [B,Cin,H,W] f32 -> xt [B,G,H,W,Cpg] fp16 (16B/pixel) ----
__global__ __launch_bounds__(256) void transpose_kernel(
    const float* __restrict__ x, uint4* __restrict__ xt)
{
    const int h = blockIdx.x, g = blockIdx.y, b = blockIdx.z;
    const int w = threadIdx.x;
    const int pix = h * W + w;
    const float* src = x + (size_t)(b * Cin + g * Cpg) * HW + pix;
    U4H v;
#pragma unroll
    for (int c = 0; c < 8; ++c) v.h[c] = (_Float16)src[(size_t)c * HW];
    xt[(size_t)(b * G + g) * HW + pix] = v.u;
}

// ---- prep: per-lane MFMA A-fragments, layout [g][m][lane] (40 KB) ----
__global__ __launch_bounds__(320) void prep_weights(
    const float* __restrict__ weight, uint4* __restrict__ wfrag)
{
    const int g    = blockIdx.x;
    const int tid  = threadIdx.x;     // 0..319
    const int m    = tid >> 6;        // 0..4
    const int lane = tid & 63;
    const int hi   = lane >> 5;
    const int lp   = lane & 31;
    const int t    = 2 * m + hi;
    U4H a;
#pragma unroll
    for (int c = 0; c < 8; ++c) {
        float v = 0.0f;
        if (lp < OPG && t < KK)
            v = weight[((size_t)(g * OPG + lp) * Cpg + c) * KK + t];
        a.h[c] = (_Float16)v;
    }
    wfrag[((size_t)g * 5 + m) * 64 + lane] = a.u;
}

// ---- cold path: boundary weights + global gathers + blend (rare) ----
__device__ __attribute__((noinline)) f16x8 slow_sample(
    const uint4* __restrict__ xb, int y0, int x0, float wy, float wx, float ms)
{
    const bool vy0 = (unsigned)y0 < (unsigned)H;
    const bool vy1 = (unsigned)(y0 + 1) < (unsigned)H;
    const bool vx0 = (unsigned)x0 < (unsigned)W;
    const bool vx1 = (unsigned)(x0 + 1) < (unsigned)W;
    const float u  = vy0 ? (1.f - wy) * ms : 0.f;
    const float vv = vy1 ? wy * ms : 0.f;
    const float ca = vx0 ? (1.f - wx) : 0.f;
    const float cb = vx1 ? wx : 0.f;
    const float w00 = u * ca, w01 = u * cb, w10 = vv * ca, w11 = vv * cb;
    const int yc0 = min(max(y0, 0), H - 1), yc1 = min(max(y0 + 1, 0), H - 1);
    const int xc0 = min(max(x0, 0), W - 1), xc1 = min(max(x0 + 1, 0), W - 1);
    U4H a, bq, c, d;
    a.u  = xb[yc0 * W + xc0];
    bq.u = xb[yc0 * W + xc1];
    c.u  = xb[yc1 * W + xc0];
    d.u  = xb[yc1 * W + xc1];
    const __half2 h00 = __float2half2_rn(w00);
    const __half2 h01 = __float2half2_rn(w01);
    const __half2 h10 = __float2half2_rn(w10);
    const __half2 h11 = __float2half2_rn(w11);
    U4H s;
#pragma unroll
    for (int i = 0; i < 4; ++i)
        s.h2[i] = __hfma2(h00, a.h2[i],
                  __hfma2(h01, bq.h2[i],
                  __hfma2(h10, c.h2[i],
                  __hmul2(h11, d.h2[i]))));
    return s.v;
}

// ---- main kernel: 256 threads, 4 rows x 128 cols per block ----
__global__ __launch_bounds__(256) void dcn_kernel(
    const uint4* __restrict__ xt,
    const uint4* __restrict__ wfrag,
    const float* __restrict__ offset,
    const float* __restrict__ mask,
    const float* __restrict__ bias,
    float* __restrict__ out)
{
    __shared__ uint4 win[WSLOTS];   // 33,360 B -> 4 blocks/CU

    // XCD-chunked bijective swizzle (4096 blocks % 8 == 0)
    const unsigned id = blockIdx.x;
    const unsigned wl = (id & (NXCD - 1)) * (gridDim.x / NXCD) + (id >> 3);
    const int colblk = wl & 1;                // W/BC = 2
    const int rowblk = (wl >> 1) & 63;        // H/BR = 64
    const int g      = (wl >> 7) & (G - 1);
    const int b      = wl >> 10;

    const int h_base = rowblk * BR;
    const int xbase  = colblk * BC;
    const int h0     = h_base - MARG;
    const int x0base = xbase - MARG;

    const int tid  = threadIdx.x;
    const int lane = tid & 63;
    const int wave = tid >> 6;                // 0..3 -> output row
    const int hi   = lane >> 5;               // tap parity in MFMA k dim
    const int lp   = lane & 31;               // A-row (out ch) / B-col (pixel)

    const int h = h_base + wave;

    const uint4* xb = xt + (size_t)(b * G + g) * HW;

    // ---- stage the 15x138 window; out-of-image slots get ZERO ----
#pragma unroll
    for (int it = 0; it < 9; ++it) {
        const int k = it * 256 + tid;
        if (k < WSLOTS) {
            const int i = k / WCOLS;
            const int j = k - i * WCOLS;
            const int gr = h0 + i;
            const int gc = x0base + j;
            const bool vld = ((unsigned)gr < (unsigned)H) & ((unsigned)gc < (unsigned)W);
            const int grc = min(max(gr, 0), H - 1);
            const int gcc = min(max(gc, 0), W - 1);
            uint4 val = xb[grc * W + gcc];
            if (!vld) val = make_uint4(0, 0, 0, 0);
            win[k] = val;
        }
    }

    const float* offy = offset + (size_t)(b * 2 + 0) * (G * KK) * HW;
    const float* offx = offset + (size_t)(b * 2 + 1) * (G * KK) * HW;
    const float* mk   = mask + (size_t)b * (G * KK) * HW;
    const uint4* wfb  = wfrag + (size_t)g * 5 * 64 + lane;

    const int pix0 = h * W + xbase + lp;

    // ---- prologue: m=0 loads (4 pixels) ----
    float dyc[4], dxc[4], mvc[4];
    U4H afc;
    {
        const int t0 = hi;
        const int oI = (G * KK - 1 - (g * KK + t0)) * HW;
        const int mI = (g * KK + t0) * HW;
#pragma unroll
        for (int q = 0; q < 4; ++q) {
            dyc[q] = offy[oI + pix0 + 32 * q];
            dxc[q] = offx[oI + pix0 + 32 * q];
            mvc[q] = mk[mI + pix0 + 32 * q];
        }
        afc.u = wfb[0];
    }

    __syncthreads();   // window ready

    // hot sample: 2-compare predicate, 4 window reads, packed blend
    auto sample = [&](float py, float px, float ms) -> f16x8 {
        const float y0f = floorf(py), x0f = floorf(px);
        const float wy = py - y0f, wx = px - x0f;
        const int y0 = (int)y0f, x0 = (int)x0f;
        const int iy0 = y0 - h0;
        const int ix0 = x0 - x0base;
        const bool ok = ((unsigned)iy0 <= (unsigned)(WROWS - 2)) &
                        ((unsigned)ix0 <= (unsigned)(WUSED - 2));
        int a0 = iy0 * WCOLS + ix0;
        a0 = ok ? a0 : 0;
        U4H a, bq, c, d;
        a.u  = win[a0];          bq.u = win[a0 + 1];
        c.u  = win[a0 + WCOLS];  d.u  = win[a0 + WCOLS + 1];
        const float u  = (1.f - wy) * ms;
        const float vv = wy * ms;
        const float w00 = u * (1.f - wx), w01 = u * wx;
        const float w10 = vv * (1.f - wx), w11 = vv * wx;
        const __half2 h00 = __float2half2_rn(w00);
        const __half2 h01 = __float2half2_rn(w01);
        const __half2 h10 = __float2half2_rn(w10);
        const __half2 h11 = __float2half2_rn(w11);
        U4H s;
#pragma unroll
        for (int i = 0; i < 4; ++i)
            s.h2[i] = __hfma2(h00, a.h2[i],
                      __hfma2(h01, bq.h2[i],
                      __hfma2(h10, c.h2[i],
                      __hmul2(h11, d.h2[i]))));
        f16x8 res = s.v;
        if (__builtin_expect(!__all((int)ok), 0)) {     // |offset| > ~4.5
            if (!ok) res = slow_sample(xb, y0, x0, wy, wx, ms);
        }
        return res;
    };

    f32x16 acc0 = {}, acc1 = {}, acc2 = {}, acc3 = {};

#pragma unroll 1
    for (int m = 0; m < 5; ++m) {
        // ---- issue next-iter loads (redundant reload of m=4 on last) ----
        const int mn  = (m < 4) ? m + 1 : 4;
        const int tn  = 2 * mn + hi;
        const int ttn = (tn > 8) ? 8 : tn;
        const int oIn = (G * KK - 1 - (g * KK + ttn)) * HW;
        const int mIn = (g * KK + ttn) * HW;
        float dyn[4], dxn[4], mvn[4];
#pragma unroll
        for (int q = 0; q < 4; ++q) {
            dyn[q] = offy[oIn + pix0 + 32 * q];
            dxn[q] = offx[oIn + pix0 + 32 * q];
            mvn[q] = mk[mIn + pix0 + 32 * q];
        }
        U4H afn; afn.u = wfb[mn * 64];

        // ---- compute current ----
        const int t  = 2 * m + hi;
        const int tt = (t > 8) ? 8 : t;
        const int ki = (tt >= 3) + (tt >= 6);
        const int kj = tt - 3 * ki;
        const float pyb = (float)(h - PAD + ki);
        const float pxb = (float)(xbase + lp - PAD + kj);

        float sg[4];
#pragma unroll
        for (int q = 0; q < 4; ++q) {
            float s = 1.0f / (1.0f + __expf(-mvc[q]));
            sg[q] = (t <= 8) ? s : 0.0f;
        }

        acc0 = __builtin_amdgcn_mfma_f32_32x32x16_f16(
            afc.v, sample(pyb + dyc[0], pxb + dxc[0], sg[0]), acc0, 0, 0, 0);
        acc1 = __builtin_amdgcn_mfma_f32_32x32x16_f16(
            afc.v, sample(pyb + dyc[1], pxb + 32.0f + dxc[1], sg[1]), acc1, 0, 0, 0);
        acc2 = __builtin_amdgcn_mfma_f32_32x32x16_f16(
            afc.v, sample(pyb + dyc[2], pxb + 64.0f + dxc[2], sg[2]), acc2, 0, 0, 0);
        acc3 = __builtin_amdgcn_mfma_f32_32x32x16_f16(
            afc.v, sample(pyb + dyc[3], pxb + 96.0f + dxc[3], sg[3]), acc3, 0, 0, 0);

        // ---- roll ----
#pragma unroll
        for (int q = 0; q < 4; ++q) {
            dyc[q] = dyn[q]; dxc[q] = dxn[q]; mvc[q] = mvn[q];
        }
        afc = afn;
    }

    // C layout: col = lp (pixel), row = (reg&3) + 8*(reg>>2) + 4*hi.
    // Useful rows 0..7 -> out channel d = reg + 4*hi (regs 0..3).
#pragma unroll
    for (int r = 0; r < 4; ++r) {
        const int dd = r + 4 * hi;
        float* ob = out + ((size_t)b * OC + g * OPG + dd) * HW + h * W + xbase + lp;
        const float bv = bias[g * OPG + dd];
        ob[0]  = acc0[r] + bv;
        ob[32] = acc1[r] + bv;
        ob[64] = acc2[r] + bv;
        ob[96] = acc3[r] + bv;
    }
}

extern "C" void kernel_launch(void* const* d_in, const int* in_sizes, int n_in,
                              void* d_out, int out_size, void* d_ws, size_t ws_size,
                              hipStream_t stream) {
    const float* x      = (const float*)d_in[0];
    const float* offset = (const float*)d_in[1];
    const float* mask   = (const float*)d_in[2];
    const float* weight = (const float*)d_in[3];
    const float* bias   = (const float*)d_in[4];
    float* out = (float*)d_out;

    uint4* xt    = (uint4*)d_ws;                                      // 32 MiB
    uint4* wfrag = (uint4*)((char*)d_ws + (size_t)B * G * HW * 16);   // 40 KiB

    dim3 tgrid(H, G, B);
    transpose_kernel<<<tgrid, dim3(256), 0, stream>>>(x, xt);
    prep_weights<<<dim3(G), dim3(320), 0, stream>>>(weight, wfrag);
    dcn_kernel<<<dim3(B * G * (H / BR) * (W / BC)), dim3(256), 0, stream>>>(
        xt, wfrag, offset, mask, bias, out);
}